// Round 1
// baseline (42829.962 us; speedup 1.0000x reference)
//
#include <hip/hip_runtime.h>
#include <hip/hip_cooperative_groups.h>

typedef __attribute__((ext_vector_type(8))) short short8;
typedef __attribute__((ext_vector_type(4))) float f32x4;

#define B_   128
#define T_   512
#define NE_  256
#define N_   1024
#define NA_  128
#define KFI  2304   /* NE + 2N */
#define KCU  1280   /* NE + N  */
#define BN   (B_ * N_)   /* 131072 */

/* workspace byte offsets (all 256-aligned), total 186,908,672 B */
#define OFF_WTFI   0UL
#define OFF_WTCU   9437184UL
#define OFF_WTH    12058624UL
#define OFF_WTOUT  16777216UL
#define OFF_XE     17039360UL
#define OFF_HBF    50593792UL
#define OFF_CBF    51118080UL
#define OFF_C32    51642368UL
#define OFF_STATES 52690944UL

__device__ __forceinline__ unsigned short f2bf(float v) {
  unsigned int u = __float_as_uint(v);
  unsigned int r = (u + 0x7fffu + ((u >> 16) & 1u)) >> 16;
  return (unsigned short)r;
}
__device__ __forceinline__ float sigm(float x) { return 1.f / (1.f + __expf(-x)); }
__device__ __forceinline__ float tanhfast(float x) { return 1.f - 2.f / (__expf(2.f * x) + 1.f); }

#define MFMA(a, b, c) __builtin_amdgcn_mfma_f32_16x16x32_bf16((a), (b), (c), 0, 0, 0)

/* ---------------- weight transpose fp32(K x N) -> bf16(N x K) ---------------- */
__global__ void transpose_to_bf16(const float* __restrict__ src,
                                  unsigned short* __restrict__ dst,
                                  int K, int N) {
  __shared__ float tile[32][33];
  const int k0 = blockIdx.y * 32, n0 = blockIdx.x * 32;
  const int tx = threadIdx.x, ty = threadIdx.y;  /* block (32,8) */
#pragma unroll
  for (int i = 0; i < 32; i += 8)
    tile[ty + i][tx] = src[(size_t)(k0 + ty + i) * N + n0 + tx];
  __syncthreads();
#pragma unroll
  for (int i = 0; i < 32; i += 8)
    dst[(size_t)(n0 + ty + i) * K + k0 + tx] = f2bf(tile[tx][ty + i]);
}

/* ---------------- embedding gather: xe[t][b][e] = bf16(emb[x[b][t]][e]) ------ */
__global__ void embed_kernel(const int* __restrict__ x, const float* __restrict__ emb,
                             unsigned short* __restrict__ xe) {
  const int r = blockIdx.x;          /* r = t*128 + b */
  const int b = r & 127, t = r >> 7;
  const int e = threadIdx.x;
  const int a = x[b * T_ + t];
  xe[(size_t)r * NE_ + e] = f2bf(emb[(size_t)a * NE_ + e]);
}

/* ---------------- zero h/c state buffers (2 MiB region) --------------------- */
__global__ void zero_ws(uint4* __restrict__ p) {
  const size_t i = (size_t)blockIdx.x * blockDim.x + threadIdx.x;
  p[i] = make_uint4(0u, 0u, 0u, 0u);
}

/* ---------------- persistent recurrent kernel ------------------------------- */
/* 256 blocks x 256 threads, cooperative. Block (mi in 4) x (ni in 64):
   32-row x 16-col tiles of fi_f / fi_i / cu (phase P) and hg (phase Q).
   4 waves split K 4-way, each wave computes both 16-row halves; LDS reduce. */
__global__ void __launch_bounds__(256) lstm_persistent(
    char* __restrict__ ws,
    const float* __restrict__ b_fi,
    const float* __restrict__ b_cu,
    const float* __restrict__ b_h) {
  const unsigned short* Wt_fi = (const unsigned short*)(ws + OFF_WTFI);
  const unsigned short* Wt_cu = (const unsigned short*)(ws + OFF_WTCU);
  const unsigned short* Wt_h  = (const unsigned short*)(ws + OFF_WTH);
  const unsigned short* xe    = (const unsigned short*)(ws + OFF_XE);
  unsigned short* hbf = (unsigned short*)(ws + OFF_HBF);
  unsigned short* cbf = (unsigned short*)(ws + OFF_CBF);
  float*          c32 = (float*)(ws + OFF_C32);
  unsigned short* states = (unsigned short*)(ws + OFF_STATES);

  cooperative_groups::grid_group grid = cooperative_groups::this_grid();

  const int blk  = blockIdx.x;
  const int xcd  = blk & 7;          /* XCD-aware swizzle: co-locate the 4 mi-  */
  const int slot = blk >> 3;         /* duplicates of a weight slice per XCD    */
  const int ni   = xcd * 8 + (slot >> 2);  /* 0..63 */
  const int mi   = slot & 3;               /* 0..3  */
  const int tid  = threadIdx.x;
  const int wave = tid >> 6;
  const int lane = tid & 63;
  const int l15  = lane & 15;
  const int quad = lane >> 4;
  const int qo   = quad * 8;
  const int n0   = ni * 16;
  const int kq   = wave;             /* K quarter */
  const int mA0  = mi * 32 + l15;    /* A-operand rows for the two m-halves */
  const int mA1  = mA0 + 16;

  const unsigned short* bfp = Wt_fi + (size_t)(n0 + l15) * KFI;
  const unsigned short* bip = Wt_fi + (size_t)(N_ + n0 + l15) * KFI;
  const unsigned short* bup = Wt_cu + (size_t)(n0 + l15) * KCU;
  const unsigned short* bhp = Wt_h  + (size_t)(n0 + l15) * KFI;

  const float bias_f = b_fi[n0 + l15];
  const float bias_i = b_fi[N_ + n0 + l15];
  const float bias_u = b_cu[n0 + l15];
  const float bias_h = b_h[n0 + l15];

  const int msubE = wave & 1;        /* elementwise partition: m-half */
  const int rbase = (wave >> 1) * 2; /* and reg pair */

  __shared__ float red[4][6][4][64]; /* [wave][acc][reg][lane] 24 KiB */

  for (int t = 0; t < T_; ++t) {
    const int cur = t & 1, prv = cur ^ 1;
    const unsigned short* xr0 = xe + ((size_t)t * B_ + mA0) * NE_;
    const unsigned short* xr1 = xe + ((size_t)t * B_ + mA1) * NE_;
    const unsigned short* hr0 = hbf + (size_t)prv * BN + (size_t)mA0 * N_;
    const unsigned short* hr1 = hbf + (size_t)prv * BN + (size_t)mA1 * N_;
    const unsigned short* cr0 = cbf + (size_t)prv * BN + (size_t)mA0 * N_;
    const unsigned short* cr1 = cbf + (size_t)prv * BN + (size_t)mA1 * N_;

    /* ---------------- Phase P: fi_f, fi_i, cu -> c2 ---------------- */
    f32x4 f0 = {0.f,0.f,0.f,0.f}, f1 = {0.f,0.f,0.f,0.f};
    f32x4 i0 = {0.f,0.f,0.f,0.f}, i1 = {0.f,0.f,0.f,0.f};
    f32x4 u0 = {0.f,0.f,0.f,0.f}, u1 = {0.f,0.f,0.f,0.f};
    {
      const int kb = kq * 576;
#pragma unroll 6
      for (int c = 0; c < 18; ++c) {
        const int k = kb + c * 32;
        const unsigned short *a0p, *a1p;
        if (k < NE_)           { a0p = xr0 + k;              a1p = xr1 + k; }
        else if (k < NE_ + N_) { a0p = hr0 + (k - NE_);      a1p = hr1 + (k - NE_); }
        else                   { a0p = cr0 + (k - NE_ - N_); a1p = cr1 + (k - NE_ - N_); }
        short8 a0 = *(const short8*)(a0p + qo);
        short8 a1 = *(const short8*)(a1p + qo);
        short8 bf = *(const short8*)(bfp + k + qo);
        short8 bi = *(const short8*)(bip + k + qo);
        f0 = MFMA(a0, bf, f0);
        f1 = MFMA(a1, bf, f1);
        i0 = MFMA(a0, bi, i0);
        i1 = MFMA(a1, bi, i1);
      }
      const int kb2 = kq * 320;
#pragma unroll 5
      for (int c = 0; c < 10; ++c) {
        const int k = kb2 + c * 32;
        const unsigned short *a0p, *a1p;
        if (k < NE_) { a0p = xr0 + k;         a1p = xr1 + k; }
        else         { a0p = hr0 + (k - NE_); a1p = hr1 + (k - NE_); }
        short8 a0 = *(const short8*)(a0p + qo);
        short8 a1 = *(const short8*)(a1p + qo);
        short8 bu = *(const short8*)(bup + k + qo);
        u0 = MFMA(a0, bu, u0);
        u1 = MFMA(a1, bu, u1);
      }
    }
#pragma unroll
    for (int r = 0; r < 4; ++r) {
      red[wave][0][r][lane] = f0[r];
      red[wave][1][r][lane] = f1[r];
      red[wave][2][r][lane] = i0[r];
      red[wave][3][r][lane] = i1[r];
      red[wave][4][r][lane] = u0[r];
      red[wave][5][r][lane] = u1[r];
    }
    __syncthreads();
    {
#pragma unroll
      for (int rr = 0; rr < 2; ++rr) {
        const int r = rbase + rr;
        float fv = red[0][msubE][r][lane] + red[1][msubE][r][lane] +
                   red[2][msubE][r][lane] + red[3][msubE][r][lane] + bias_f;
        float iv = red[0][2 + msubE][r][lane] + red[1][2 + msubE][r][lane] +
                   red[2][2 + msubE][r][lane] + red[3][2 + msubE][r][lane] + bias_i;
        float uv = red[0][4 + msubE][r][lane] + red[1][4 + msubE][r][lane] +
                   red[2][4 + msubE][r][lane] + red[3][4 + msubE][r][lane] + bias_u;
        const int m = mi * 32 + msubE * 16 + quad * 4 + r;
        const size_t idx = (size_t)m * N_ + n0 + l15;
        const float cold = c32[(size_t)prv * BN + idx];
        const float c2v = sigm(fv) * cold + sigm(iv) * tanhfast(uv);
        c32[(size_t)cur * BN + idx] = c2v;
        cbf[(size_t)cur * BN + idx] = f2bf(c2v);
      }
    }
    grid.sync();

    /* ---------------- Phase Q: hg -> h2 ---------------- */
    const unsigned short* c2r0 = cbf + (size_t)cur * BN + (size_t)mA0 * N_;
    const unsigned short* c2r1 = cbf + (size_t)cur * BN + (size_t)mA1 * N_;
    f32x4 h0 = {0.f,0.f,0.f,0.f}, h1 = {0.f,0.f,0.f,0.f};
    {
      const int kb = kq * 576;
#pragma unroll 6
      for (int c = 0; c < 18; ++c) {
        const int k = kb + c * 32;
        const unsigned short *a0p, *a1p;
        if (k < NE_)           { a0p = xr0 + k;               a1p = xr1 + k; }
        else if (k < NE_ + N_) { a0p = hr0 + (k - NE_);       a1p = hr1 + (k - NE_); }
        else                   { a0p = c2r0 + (k - NE_ - N_); a1p = c2r1 + (k - NE_ - N_); }
        short8 a0 = *(const short8*)(a0p + qo);
        short8 a1 = *(const short8*)(a1p + qo);
        short8 bh = *(const short8*)(bhp + k + qo);
        h0 = MFMA(a0, bh, h0);
        h1 = MFMA(a1, bh, h1);
      }
    }
#pragma unroll
    for (int r = 0; r < 4; ++r) {
      red[wave][0][r][lane] = h0[r];
      red[wave][1][r][lane] = h1[r];
    }
    __syncthreads();
    {
#pragma unroll
      for (int rr = 0; rr < 2; ++rr) {
        const int r = rbase + rr;
        float hv = red[0][msubE][r][lane] + red[1][msubE][r][lane] +
                   red[2][msubE][r][lane] + red[3][msubE][r][lane] + bias_h;
        const int m = mi * 32 + msubE * 16 + quad * 4 + r;
        const size_t idx = (size_t)m * N_ + n0 + l15;
        const float c2v = c32[(size_t)cur * BN + idx];
        const float h2 = hv * tanhfast(c2v);
        const unsigned short hb = f2bf(h2);
        hbf[(size_t)cur * BN + idx] = hb;
        states[((size_t)m * T_ + t) * N_ + n0 + l15] = hb;
      }
    }
    grid.sync();
  }
}

/* ---------------- epilogue: y = states @ W_out + b_out ---------------------- */
__global__ void __launch_bounds__(256) out_gemm(const char* __restrict__ ws,
                                                const float* __restrict__ b_out,
                                                float* __restrict__ y) {
  const unsigned short* states = (const unsigned short*)(ws + OFF_STATES);
  const unsigned short* Wt_out = (const unsigned short*)(ws + OFF_WTOUT);
  const int tid = threadIdx.x, wave = tid >> 6, lane = tid & 63;
  const int l15 = lane & 15, quad = lane >> 4, qo = quad * 8;
  const int msub = wave & 1, npair = wave >> 1;
  const size_t r0 = (size_t)blockIdx.x * 32;
  const unsigned short* arow = states + (r0 + msub * 16 + l15) * N_;
  const unsigned short* b0p = Wt_out + (size_t)(npair * 64 + 0  + l15) * N_;
  const unsigned short* b1p = Wt_out + (size_t)(npair * 64 + 16 + l15) * N_;
  const unsigned short* b2p = Wt_out + (size_t)(npair * 64 + 32 + l15) * N_;
  const unsigned short* b3p = Wt_out + (size_t)(npair * 64 + 48 + l15) * N_;
  f32x4 a0 = {0.f,0.f,0.f,0.f}, a1 = {0.f,0.f,0.f,0.f};
  f32x4 a2 = {0.f,0.f,0.f,0.f}, a3 = {0.f,0.f,0.f,0.f};
#pragma unroll 8
  for (int c = 0; c < 32; ++c) {
    const int k = c * 32;
    short8 av = *(const short8*)(arow + k + qo);
    a0 = MFMA(av, *(const short8*)(b0p + k + qo), a0);
    a1 = MFMA(av, *(const short8*)(b1p + k + qo), a1);
    a2 = MFMA(av, *(const short8*)(b2p + k + qo), a2);
    a3 = MFMA(av, *(const short8*)(b3p + k + qo), a3);
  }
#pragma unroll
  for (int r = 0; r < 4; ++r) {
    const size_t m = r0 + msub * 16 + quad * 4 + r;
    y[m * NA_ + npair * 64 + 0  + l15] = a0[r] + b_out[npair * 64 + 0  + l15];
    y[m * NA_ + npair * 64 + 16 + l15] = a1[r] + b_out[npair * 64 + 16 + l15];
    y[m * NA_ + npair * 64 + 32 + l15] = a2[r] + b_out[npair * 64 + 32 + l15];
    y[m * NA_ + npair * 64 + 48 + l15] = a3[r] + b_out[npair * 64 + 48 + l15];
  }
}

/* ---------------- host ------------------------------------------------------ */
extern "C" void kernel_launch(void* const* d_in, const int* in_sizes, int n_in,
                              void* d_out, int out_size, void* d_ws, size_t ws_size,
                              hipStream_t stream) {
  const int*   x     = (const int*)d_in[0];
  const float* emb   = (const float*)d_in[1];
  const float* W_fi  = (const float*)d_in[2];
  const float* b_fi  = (const float*)d_in[3];
  const float* W_cu  = (const float*)d_in[4];
  const float* b_cu  = (const float*)d_in[5];
  const float* W_h   = (const float*)d_in[6];
  const float* b_h   = (const float*)d_in[7];
  const float* W_out = (const float*)d_in[8];
  const float* b_out = (const float*)d_in[9];
  char* ws = (char*)d_ws;
  float* y = (float*)d_out;
  (void)in_sizes; (void)n_in; (void)out_size; (void)ws_size; /* needs ~187 MB ws */

  /* weight transposes fp32 -> bf16 (N x K) */
  transpose_to_bf16<<<dim3(2048 / 32, 2304 / 32), dim3(32, 8), 0, stream>>>(
      W_fi, (unsigned short*)(ws + OFF_WTFI), KFI, 2048);
  transpose_to_bf16<<<dim3(1024 / 32, 1280 / 32), dim3(32, 8), 0, stream>>>(
      W_cu, (unsigned short*)(ws + OFF_WTCU), KCU, 1024);
  transpose_to_bf16<<<dim3(1024 / 32, 2304 / 32), dim3(32, 8), 0, stream>>>(
      W_h, (unsigned short*)(ws + OFF_WTH), KFI, 1024);
  transpose_to_bf16<<<dim3(128 / 32, 1024 / 32), dim3(32, 8), 0, stream>>>(
      W_out, (unsigned short*)(ws + OFF_WTOUT), N_, 128);

  embed_kernel<<<T_ * B_, NE_, 0, stream>>>(x, emb, (unsigned short*)(ws + OFF_XE));

  /* zero hbf/cbf/c32 (contiguous 2 MiB region) */
  zero_ws<<<512, 256, 0, stream>>>((uint4*)(ws + OFF_HBF));

  char* wsp = ws;
  void* kargs[4] = { (void*)&wsp, (void*)&b_fi, (void*)&b_cu, (void*)&b_h };
  hipLaunchCooperativeKernel((void*)lstm_persistent, dim3(256), dim3(256),
                             kargs, 0, stream);

  out_gemm<<<(B_ * T_) / 32, 256, 0, stream>>>(ws, b_out, y);
}

// Round 2
// 22599.934 us; speedup vs baseline: 1.8951x; 1.8951x over previous
//
#include <hip/hip_runtime.h>

typedef __attribute__((ext_vector_type(8))) short short8;
typedef __attribute__((ext_vector_type(4))) float f32x4;

#define B_   128
#define T_   512
#define NE_  256
#define N_   1024
#define NA_  128
#define KFI  2304   /* NE + 2N */
#define KCU  1280   /* NE + N  */
#define BN   (B_ * N_)   /* 131072 */
#define NBLK 256

/* workspace byte offsets (all 256-aligned), total 186,908,928 B */
#define OFF_WTFI   0UL
#define OFF_WTCU   9437184UL
#define OFF_WTH    12058624UL
#define OFF_WTOUT  16777216UL
#define OFF_XE     17039360UL
#define OFF_CTR    50593792UL   /* 256 B: ctrP @ +0, ctrQ @ +128 */
#define OFF_HBF    50594048UL
#define OFF_CBF    51118336UL
#define OFF_C32    51642624UL
#define OFF_STATES 52691200UL

__device__ __forceinline__ unsigned short f2bf(float v) {
  unsigned int u = __float_as_uint(v);
  unsigned int r = (u + 0x7fffu + ((u >> 16) & 1u)) >> 16;
  return (unsigned short)r;
}
__device__ __forceinline__ float sigm(float x) { return 1.f / (1.f + __expf(-x)); }
__device__ __forceinline__ float tanhfast(float x) { return 1.f - 2.f / (__expf(2.f * x) + 1.f); }

#define MFMA(a, b, c) __builtin_amdgcn_mfma_f32_16x16x32_bf16((a), (b), (c), 0, 0, 0)

/* ---------------- weight transpose fp32(K x N) -> bf16(N x K) ---------------- */
__global__ void transpose_to_bf16(const float* __restrict__ src,
                                  unsigned short* __restrict__ dst,
                                  int K, int N) {
  __shared__ float tile[32][33];
  const int k0 = blockIdx.y * 32, n0 = blockIdx.x * 32;
  const int tx = threadIdx.x, ty = threadIdx.y;  /* block (32,8) */
#pragma unroll
  for (int i = 0; i < 32; i += 8)
    tile[ty + i][tx] = src[(size_t)(k0 + ty + i) * N + n0 + tx];
  __syncthreads();
#pragma unroll
  for (int i = 0; i < 32; i += 8)
    dst[(size_t)(n0 + ty + i) * K + k0 + tx] = f2bf(tile[tx][ty + i]);
}

/* ---------------- embedding gather: xe[t][b][e] = bf16(emb[x[b][t]][e]) ------ */
__global__ void embed_kernel(const int* __restrict__ x, const float* __restrict__ emb,
                             unsigned short* __restrict__ xe) {
  const int r = blockIdx.x;          /* r = t*128 + b */
  const int b = r & 127, t = r >> 7;
  const int e = threadIdx.x;
  const int a = x[b * T_ + t];
  xe[(size_t)r * NE_ + e] = f2bf(emb[(size_t)a * NE_ + e]);
}

/* ---------------- zero counters + h/c state buffers ------------------------- */
__global__ void zero_ws(uint4* __restrict__ p, int n16) {
  const int i = blockIdx.x * blockDim.x + threadIdx.x;
  if (i < n16) p[i] = make_uint4(0u, 0u, 0u, 0u);
}

/* ---------------- persistent recurrent kernel ------------------------------- */
/* 256 blocks x 256 threads, cooperative launch (co-residency guarantee).
   Block (mi in 4) x (ni in 64): 32-row x 16-col gate tiles. 4 waves split K
   by interleaved 32-chunks (chunk g = wave + 4*c); LDS reduce.
   Custom flag barrier replaces grid.sync:
     arrive: threadfence_block + syncthreads (drain all waves' stores to L2),
             tid0: agent release fence (buffer_wbl2) + relaxed atomicAdd.
     wait:   tid0 spins on relaxed agent atomic load, agent acquire fence
             (buffer_inv), syncthreads.
   P(t) waits ctrQ >= 256t (h(t-1); implies c(t-1) ready via program order).
   Q(t) waits ctrP >= 256(t+1) (c2(t)); its x/h-part MFMAs issue pre-wait. */
__global__ void __launch_bounds__(256) lstm_persistent(
    char* __restrict__ ws,
    const float* __restrict__ b_fi,
    const float* __restrict__ b_cu,
    const float* __restrict__ b_h) {
  const unsigned short* Wt_fi = (const unsigned short*)(ws + OFF_WTFI);
  const unsigned short* Wt_cu = (const unsigned short*)(ws + OFF_WTCU);
  const unsigned short* Wt_h  = (const unsigned short*)(ws + OFF_WTH);
  const unsigned short* xe    = (const unsigned short*)(ws + OFF_XE);
  unsigned short* hbf = (unsigned short*)(ws + OFF_HBF);
  unsigned short* cbf = (unsigned short*)(ws + OFF_CBF);
  float*          c32 = (float*)(ws + OFF_C32);
  unsigned short* states = (unsigned short*)(ws + OFF_STATES);
  unsigned int* ctrP = (unsigned int*)(ws + OFF_CTR);
  unsigned int* ctrQ = (unsigned int*)(ws + OFF_CTR + 128);

  const int blk  = blockIdx.x;
  const int xcd  = blk & 7;          /* XCD-aware swizzle: co-locate the 4 mi-  */
  const int slot = blk >> 3;         /* duplicates of a weight slice per XCD    */
  const int ni   = xcd * 8 + (slot >> 2);  /* 0..63 */
  const int mi   = slot & 3;               /* 0..3  */
  const int tid  = threadIdx.x;
  const int wave = tid >> 6;
  const int lane = tid & 63;
  const int l15  = lane & 15;
  const int quad = lane >> 4;
  const int qo   = quad * 8;
  const int n0   = ni * 16;
  const int kq   = wave;             /* K chunk interleave phase */
  const int mA0  = mi * 32 + l15;    /* A-operand rows for the two m-halves */
  const int mA1  = mA0 + 16;

  const unsigned short* bfp = Wt_fi + (size_t)(n0 + l15) * KFI;
  const unsigned short* bip = Wt_fi + (size_t)(N_ + n0 + l15) * KFI;
  const unsigned short* bup = Wt_cu + (size_t)(n0 + l15) * KCU;
  const unsigned short* bhp = Wt_h  + (size_t)(n0 + l15) * KFI;

  const float bias_f = b_fi[n0 + l15];
  const float bias_i = b_fi[N_ + n0 + l15];
  const float bias_u = b_cu[n0 + l15];
  const float bias_h = b_h[n0 + l15];

  const int msubE = wave & 1;        /* elementwise partition: m-half */
  const int rbase = (wave >> 1) * 2; /* and reg pair */

  __shared__ float red[4][6][4][64]; /* [wave][acc][reg][lane] 24 KiB */

  float c2keep[2];                   /* carry c2 from P-elementwise to Q */

  for (int t = 0; t < T_; ++t) {
    const int cur = t & 1, prv = cur ^ 1;
    const unsigned short* xr0 = xe + ((size_t)t * B_ + mA0) * NE_;
    const unsigned short* xr1 = xe + ((size_t)t * B_ + mA1) * NE_;
    const unsigned short* hr0 = hbf + (size_t)prv * BN + (size_t)mA0 * N_;
    const unsigned short* hr1 = hbf + (size_t)prv * BN + (size_t)mA1 * N_;
    const unsigned short* cr0 = cbf + (size_t)prv * BN + (size_t)mA0 * N_;
    const unsigned short* cr1 = cbf + (size_t)prv * BN + (size_t)mA1 * N_;

    /* ---- wait: h(t-1), c(t-1) published ---- */
    if (tid == 0) {
      const unsigned tgt = (unsigned)(NBLK * t);
      while (__hip_atomic_load(ctrQ, __ATOMIC_RELAXED, __HIP_MEMORY_SCOPE_AGENT) < tgt) { }
      __builtin_amdgcn_fence(__ATOMIC_ACQUIRE, "agent");
    }
    __syncthreads();

    /* ---------------- Phase P: fi_f, fi_i, cu -> c2 ---------------- */
    f32x4 f0 = {0.f,0.f,0.f,0.f}, f1 = {0.f,0.f,0.f,0.f};
    f32x4 i0 = {0.f,0.f,0.f,0.f}, i1 = {0.f,0.f,0.f,0.f};
    f32x4 u0 = {0.f,0.f,0.f,0.f}, u1 = {0.f,0.f,0.f,0.f};
#pragma unroll 6
    for (int c = 0; c < 18; ++c) {
      const int k = (kq + 4 * c) * 32;
      const unsigned short *a0p, *a1p;
      if (k < NE_)           { a0p = xr0 + k;              a1p = xr1 + k; }
      else if (k < NE_ + N_) { a0p = hr0 + (k - NE_);      a1p = hr1 + (k - NE_); }
      else                   { a0p = cr0 + (k - NE_ - N_); a1p = cr1 + (k - NE_ - N_); }
      short8 a0 = *(const short8*)(a0p + qo);
      short8 a1 = *(const short8*)(a1p + qo);
      short8 bf = *(const short8*)(bfp + k + qo);
      short8 bi = *(const short8*)(bip + k + qo);
      f0 = MFMA(a0, bf, f0);
      f1 = MFMA(a1, bf, f1);
      i0 = MFMA(a0, bi, i0);
      i1 = MFMA(a1, bi, i1);
    }
#pragma unroll 5
    for (int c = 0; c < 10; ++c) {
      const int k = (kq + 4 * c) * 32;
      const unsigned short *a0p, *a1p;
      if (k < NE_) { a0p = xr0 + k;         a1p = xr1 + k; }
      else         { a0p = hr0 + (k - NE_); a1p = hr1 + (k - NE_); }
      short8 a0 = *(const short8*)(a0p + qo);
      short8 a1 = *(const short8*)(a1p + qo);
      short8 bu = *(const short8*)(bup + k + qo);
      u0 = MFMA(a0, bu, u0);
      u1 = MFMA(a1, bu, u1);
    }
#pragma unroll
    for (int r = 0; r < 4; ++r) {
      red[wave][0][r][lane] = f0[r];
      red[wave][1][r][lane] = f1[r];
      red[wave][2][r][lane] = i0[r];
      red[wave][3][r][lane] = i1[r];
      red[wave][4][r][lane] = u0[r];
      red[wave][5][r][lane] = u1[r];
    }
    __syncthreads();
    {
#pragma unroll
      for (int rr = 0; rr < 2; ++rr) {
        const int r = rbase + rr;
        float fv = red[0][msubE][r][lane] + red[1][msubE][r][lane] +
                   red[2][msubE][r][lane] + red[3][msubE][r][lane] + bias_f;
        float iv = red[0][2 + msubE][r][lane] + red[1][2 + msubE][r][lane] +
                   red[2][2 + msubE][r][lane] + red[3][2 + msubE][r][lane] + bias_i;
        float uv = red[0][4 + msubE][r][lane] + red[1][4 + msubE][r][lane] +
                   red[2][4 + msubE][r][lane] + red[3][4 + msubE][r][lane] + bias_u;
        const int m = mi * 32 + msubE * 16 + quad * 4 + r;
        const size_t idx = (size_t)m * N_ + n0 + l15;
        const float cold = c32[(size_t)prv * BN + idx];
        const float c2v = sigm(fv) * cold + sigm(iv) * tanhfast(uv);
        c2keep[rr] = c2v;
        c32[(size_t)cur * BN + idx] = c2v;
        cbf[(size_t)cur * BN + idx] = f2bf(c2v);
      }
    }
    /* ---- arrive P: publish c2(t) ---- */
    __threadfence_block();
    __syncthreads();
    if (tid == 0) {
      __builtin_amdgcn_fence(__ATOMIC_RELEASE, "agent");
      __hip_atomic_fetch_add(ctrP, 1u, __ATOMIC_RELAXED, __HIP_MEMORY_SCOPE_AGENT);
    }

    /* ---------------- Phase Q: hg -> h2 ---------------- */
    /* pre-pass: x+h K-chunks (k < 1280), independent of c2(t) */
    f32x4 h0 = {0.f,0.f,0.f,0.f}, h1 = {0.f,0.f,0.f,0.f};
#pragma unroll 5
    for (int c = 0; c < 10; ++c) {
      const int k = (kq + 4 * c) * 32;
      const unsigned short *a0p, *a1p;
      if (k < NE_) { a0p = xr0 + k;         a1p = xr1 + k; }
      else         { a0p = hr0 + (k - NE_); a1p = hr1 + (k - NE_); }
      short8 a0 = *(const short8*)(a0p + qo);
      short8 a1 = *(const short8*)(a1p + qo);
      short8 bh = *(const short8*)(bhp + k + qo);
      h0 = MFMA(a0, bh, h0);
      h1 = MFMA(a1, bh, h1);
    }
    /* ---- wait: c2(t) published by all blocks ---- */
    if (tid == 0) {
      const unsigned tgt = (unsigned)(NBLK * (t + 1));
      while (__hip_atomic_load(ctrP, __ATOMIC_RELAXED, __HIP_MEMORY_SCOPE_AGENT) < tgt) { }
      __builtin_amdgcn_fence(__ATOMIC_ACQUIRE, "agent");
    }
    __syncthreads();
    /* post-pass: c2 K-chunks (k >= 1280) */
    const unsigned short* c2r0 = cbf + (size_t)cur * BN + (size_t)mA0 * N_;
    const unsigned short* c2r1 = cbf + (size_t)cur * BN + (size_t)mA1 * N_;
#pragma unroll 4
    for (int c = 10; c < 18; ++c) {
      const int k = (kq + 4 * c) * 32;
      short8 a0 = *(const short8*)(c2r0 + (k - NE_ - N_) + qo);
      short8 a1 = *(const short8*)(c2r1 + (k - NE_ - N_) + qo);
      short8 bh = *(const short8*)(bhp + k + qo);
      h0 = MFMA(a0, bh, h0);
      h1 = MFMA(a1, bh, h1);
    }
#pragma unroll
    for (int r = 0; r < 4; ++r) {
      red[wave][0][r][lane] = h0[r];
      red[wave][1][r][lane] = h1[r];
    }
    __syncthreads();
    {
#pragma unroll
      for (int rr = 0; rr < 2; ++rr) {
        const int r = rbase + rr;
        float hv = red[0][msubE][r][lane] + red[1][msubE][r][lane] +
                   red[2][msubE][r][lane] + red[3][msubE][r][lane] + bias_h;
        const int m = mi * 32 + msubE * 16 + quad * 4 + r;
        const size_t idx = (size_t)m * N_ + n0 + l15;
        const float h2 = hv * tanhfast(c2keep[rr]);
        const unsigned short hb = f2bf(h2);
        hbf[(size_t)cur * BN + idx] = hb;
        states[((size_t)m * T_ + t) * N_ + n0 + l15] = hb;
      }
    }
    /* ---- arrive Q: publish h(t) ---- */
    __threadfence_block();
    __syncthreads();
    if (tid == 0) {
      __builtin_amdgcn_fence(__ATOMIC_RELEASE, "agent");
      __hip_atomic_fetch_add(ctrQ, 1u, __ATOMIC_RELAXED, __HIP_MEMORY_SCOPE_AGENT);
    }
  }
}

/* ---------------- epilogue: y = states @ W_out + b_out ---------------------- */
__global__ void __launch_bounds__(256) out_gemm(const char* __restrict__ ws,
                                                const float* __restrict__ b_out,
                                                float* __restrict__ y) {
  const unsigned short* states = (const unsigned short*)(ws + OFF_STATES);
  const unsigned short* Wt_out = (const unsigned short*)(ws + OFF_WTOUT);
  const int tid = threadIdx.x, wave = tid >> 6, lane = tid & 63;
  const int l15 = lane & 15, quad = lane >> 4, qo = quad * 8;
  const int msub = wave & 1, npair = wave >> 1;
  const size_t r0 = (size_t)blockIdx.x * 32;
  const unsigned short* arow = states + (r0 + msub * 16 + l15) * N_;
  const unsigned short* b0p = Wt_out + (size_t)(npair * 64 + 0  + l15) * N_;
  const unsigned short* b1p = Wt_out + (size_t)(npair * 64 + 16 + l15) * N_;
  const unsigned short* b2p = Wt_out + (size_t)(npair * 64 + 32 + l15) * N_;
  const unsigned short* b3p = Wt_out + (size_t)(npair * 64 + 48 + l15) * N_;
  f32x4 a0 = {0.f,0.f,0.f,0.f}, a1 = {0.f,0.f,0.f,0.f};
  f32x4 a2 = {0.f,0.f,0.f,0.f}, a3 = {0.f,0.f,0.f,0.f};
#pragma unroll 8
  for (int c = 0; c < 32; ++c) {
    const int k = c * 32;
    short8 av = *(const short8*)(arow + k + qo);
    a0 = MFMA(av, *(const short8*)(b0p + k + qo), a0);
    a1 = MFMA(av, *(const short8*)(b1p + k + qo), a1);
    a2 = MFMA(av, *(const short8*)(b2p + k + qo), a2);
    a3 = MFMA(av, *(const short8*)(b3p + k + qo), a3);
  }
#pragma unroll
  for (int r = 0; r < 4; ++r) {
    const size_t m = r0 + msub * 16 + quad * 4 + r;
    y[m * NA_ + npair * 64 + 0  + l15] = a0[r] + b_out[npair * 64 + 0  + l15];
    y[m * NA_ + npair * 64 + 16 + l15] = a1[r] + b_out[npair * 64 + 16 + l15];
    y[m * NA_ + npair * 64 + 32 + l15] = a2[r] + b_out[npair * 64 + 32 + l15];
    y[m * NA_ + npair * 64 + 48 + l15] = a3[r] + b_out[npair * 64 + 48 + l15];
  }
}

/* ---------------- host ------------------------------------------------------ */
extern "C" void kernel_launch(void* const* d_in, const int* in_sizes, int n_in,
                              void* d_out, int out_size, void* d_ws, size_t ws_size,
                              hipStream_t stream) {
  const int*   x     = (const int*)d_in[0];
  const float* emb   = (const float*)d_in[1];
  const float* W_fi  = (const float*)d_in[2];
  const float* b_fi  = (const float*)d_in[3];
  const float* W_cu  = (const float*)d_in[4];
  const float* b_cu  = (const float*)d_in[5];
  const float* W_h   = (const float*)d_in[6];
  const float* b_h   = (const float*)d_in[7];
  const float* W_out = (const float*)d_in[8];
  const float* b_out = (const float*)d_in[9];
  char* ws = (char*)d_ws;
  float* y = (float*)d_out;
  (void)in_sizes; (void)n_in; (void)out_size; (void)ws_size; /* needs ~187 MB ws */

  /* weight transposes fp32 -> bf16 (N x K) */
  transpose_to_bf16<<<dim3(2048 / 32, 2304 / 32), dim3(32, 8), 0, stream>>>(
      W_fi, (unsigned short*)(ws + OFF_WTFI), KFI, 2048);
  transpose_to_bf16<<<dim3(1024 / 32, 1280 / 32), dim3(32, 8), 0, stream>>>(
      W_cu, (unsigned short*)(ws + OFF_WTCU), KCU, 1024);
  transpose_to_bf16<<<dim3(1024 / 32, 2304 / 32), dim3(32, 8), 0, stream>>>(
      W_h, (unsigned short*)(ws + OFF_WTH), KFI, 1024);
  transpose_to_bf16<<<dim3(128 / 32, 1024 / 32), dim3(32, 8), 0, stream>>>(
      W_out, (unsigned short*)(ws + OFF_WTOUT), N_, 128);

  embed_kernel<<<T_ * B_, NE_, 0, stream>>>(x, emb, (unsigned short*)(ws + OFF_XE));

  /* zero ctr + hbf + cbf + c32 (contiguous 2 MiB + 256 B region) */
  const int n16 = (int)((OFF_STATES - OFF_CTR) / 16);  /* 131088 */
  zero_ws<<<(n16 + 255) / 256, 256, 0, stream>>>((uint4*)(ws + OFF_CTR), n16);

  char* wsp = ws;
  void* kargs[4] = { (void*)&wsp, (void*)&b_fi, (void*)&b_cu, (void*)&b_h };
  hipLaunchCooperativeKernel((void*)lstm_persistent, dim3(256), dim3(256),
                             kargs, 0, stream);

  out_gemm<<<(B_ * T_) / 32, 256, 0, stream>>>(ws, b_out, y);
}

// Round 3
// 10659.473 us; speedup vs baseline: 4.0180x; 2.1202x over previous
//
#include <hip/hip_runtime.h>

typedef __attribute__((ext_vector_type(8))) short short8;
typedef __attribute__((ext_vector_type(4))) float f32x4;

#define B_   128
#define T_   512
#define NE_  256
#define N_   1024
#define NA_  128
#define KFI  2304   /* NE + 2N */
#define KCU  1280   /* NE + N  */
#define BN   (B_ * N_)   /* 131072 */
#define TS   513         /* T + 1 state slots (slot 0 = zeros) */

/* workspace byte offsets, total 185,600,000 B */
#define OFF_WTFI   0UL
#define OFF_WTCU   9437184UL
#define OFF_WTH    12058624UL
#define OFF_WTOUT  16777216UL
#define OFF_XE     17039360UL
#define OFF_FLAGS  50593792UL   /* flagsP 1 KiB | flagsQ 1 KiB */
#define OFF_CBF    50595840UL   /* 2 x B x N bf16 = 512 KiB     */
#define OFF_STATES 51120128UL   /* 128 x 513 x 1024 bf16 = h history + output states */

__device__ __forceinline__ unsigned short f2bf(float v) {
  unsigned int u = __float_as_uint(v);
  unsigned int r = (u + 0x7fffu + ((u >> 16) & 1u)) >> 16;
  return (unsigned short)r;
}
__device__ __forceinline__ float sigm(float x) { return 1.f / (1.f + __expf(-x)); }
__device__ __forceinline__ float tanhfast(float x) { return 1.f - 2.f / (__expf(2.f * x) + 1.f); }

#define MFMA(a, b, c) __builtin_amdgcn_mfma_f32_16x16x32_bf16((a), (b), (c), 0, 0, 0)

/* 16B state load that bypasses (possibly stale) L1/L2: two agent-scope
   relaxed atomic 8B loads -> global_load_dwordx2 sc0 sc1 (reads IF). */
__device__ __forceinline__ short8 ld8_agent(const unsigned short* p) {
  union { unsigned long long q[2]; short8 v; } u;
  u.q[0] = __hip_atomic_load((unsigned long long*)p,     __ATOMIC_RELAXED, __HIP_MEMORY_SCOPE_AGENT);
  u.q[1] = __hip_atomic_load((unsigned long long*)p + 1, __ATOMIC_RELAXED, __HIP_MEMORY_SCOPE_AGENT);
  return u.v;
}

/* ---------------- weight transpose fp32(K x N) -> bf16(N x K) ---------------- */
__global__ void transpose_to_bf16(const float* __restrict__ src,
                                  unsigned short* __restrict__ dst,
                                  int K, int N) {
  __shared__ float tile[32][33];
  const int k0 = blockIdx.y * 32, n0 = blockIdx.x * 32;
  const int tx = threadIdx.x, ty = threadIdx.y;  /* block (32,8) */
#pragma unroll
  for (int i = 0; i < 32; i += 8)
    tile[ty + i][tx] = src[(size_t)(k0 + ty + i) * N + n0 + tx];
  __syncthreads();
#pragma unroll
  for (int i = 0; i < 32; i += 8)
    dst[(size_t)(n0 + ty + i) * K + k0 + tx] = f2bf(tile[tx][ty + i]);
}

/* ---------------- embedding gather: xe[t][b][e] = bf16(emb[x[b][t]][e]) ------ */
__global__ void embed_kernel(const int* __restrict__ x, const float* __restrict__ emb,
                             unsigned short* __restrict__ xe) {
  const int r = blockIdx.x;          /* r = t*128 + b */
  const int b = r & 127, t = r >> 7;
  const int e = threadIdx.x;
  const int a = x[b * T_ + t];
  xe[(size_t)r * NE_ + e] = f2bf(emb[(size_t)a * NE_ + e]);
}

/* ---------------- zero flags + cbf (sc1 stores -> visible to IF readers) ---- */
__global__ void zero_sync_region(char* __restrict__ ws) {
  unsigned* p = (unsigned*)(ws + OFF_FLAGS);
  const int i = blockIdx.x * blockDim.x + threadIdx.x;
  if (i < (int)((OFF_STATES - OFF_FLAGS) / 4))
    __hip_atomic_store(p + i, 0u, __ATOMIC_RELAXED, __HIP_MEMORY_SCOPE_AGENT);
}

/* ---------------- zero h slot 0 for each batch row -------------------------- */
__global__ void zero_h0(char* __restrict__ ws) {
  unsigned* st = (unsigned*)(ws + OFF_STATES);
  unsigned* row = st + (size_t)blockIdx.x * TS * 512;  /* u32 units: 512/row */
  __hip_atomic_store(row + threadIdx.x,       0u, __ATOMIC_RELAXED, __HIP_MEMORY_SCOPE_AGENT);
  __hip_atomic_store(row + 256 + threadIdx.x, 0u, __ATOMIC_RELAXED, __HIP_MEMORY_SCOPE_AGENT);
}

/* ---------------- persistent recurrent kernel ------------------------------- */
/* 256 blocks x 256 threads, cooperative (co-residency). Block (mi in 4) x
   (ni in 64): 32-row x 16-col gate tiles; 4 waves split K via interleaved
   32-chunks. The 4 mi-groups are independent LSTMs (batch partition) -> all
   sync is within the 64 same-mi blocks via per-block flags; state crosses
   XCDs through IF (sc1 stores / sc1-or-NT loads); weights & xe use normal
   loads and stay L2-resident (no cache flush instructions anywhere). */
__global__ void __launch_bounds__(256) lstm_persistent(
    char* __restrict__ ws,
    const float* __restrict__ b_fi,
    const float* __restrict__ b_cu,
    const float* __restrict__ b_h) {
  const unsigned short* Wt_fi = (const unsigned short*)(ws + OFF_WTFI);
  const unsigned short* Wt_cu = (const unsigned short*)(ws + OFF_WTCU);
  const unsigned short* Wt_h  = (const unsigned short*)(ws + OFF_WTH);
  const unsigned short* xe    = (const unsigned short*)(ws + OFF_XE);
  unsigned short* cbf = (unsigned short*)(ws + OFF_CBF);
  unsigned*       cbf32 = (unsigned*)(ws + OFF_CBF);
  unsigned short* states = (unsigned short*)(ws + OFF_STATES);
  unsigned*       states32 = (unsigned*)(ws + OFF_STATES);
  unsigned* flagsP = (unsigned*)(ws + OFF_FLAGS);
  unsigned* flagsQ = flagsP + 256;

  const int blk  = blockIdx.x;
  const int xcd  = blk & 7;          /* 4 mi share each ni-slice on one XCD ->  */
  const int slot = blk >> 3;         /* 2.1 MB unique weights/XCD, L2-resident  */
  const int ni   = xcd * 8 + (slot >> 2);  /* 0..63 */
  const int mi   = slot & 3;               /* 0..3  */
  const int tid  = threadIdx.x;
  const int wave = tid >> 6;
  const int lane = tid & 63;
  const int l15  = lane & 15;
  const int quad = lane >> 4;
  const int qo   = quad * 8;
  const int n0   = ni * 16;
  const int mA0  = mi * 32 + l15;
  const int mA1  = mA0 + 16;

  const unsigned short* bfp = Wt_fi + (size_t)(n0 + l15) * KFI;
  const unsigned short* bip = Wt_fi + (size_t)(N_ + n0 + l15) * KFI;
  const unsigned short* bup = Wt_cu + (size_t)(n0 + l15) * KCU;
  const unsigned short* bhp = Wt_h  + (size_t)(n0 + l15) * KFI;

  unsigned* gflagP = flagsP + mi * 64;
  unsigned* gflagQ = flagsQ + mi * 64;

  __shared__ float red[4][6][4][64]; /* [wave][acc][reg][lane] 24 KiB */
  __shared__ float sb[4][16];        /* biases f,i,u,h for this block's 16 cols */
  if (tid < 64) {
    const int g = tid >> 4, col = tid & 15;
    float v;
    if      (g == 0) v = b_fi[n0 + col];
    else if (g == 1) v = b_fi[N_ + n0 + col];
    else if (g == 2) v = b_cu[n0 + col];
    else             v = b_h[n0 + col];
    sb[g][col] = v;
  }

  /* elementwise mapping: thread -> (row_l in 32, col pair) */
  const int row_l = tid >> 3;
  const int colp  = tid & 7;
  const int gh    = row_l >> 4;        /* m-half -> acc parity */
  const int re    = row_l & 3;         /* acc reg */
  const int lbase = ((row_l >> 2) & 3) * 16 + colp * 2;
  const int me    = mi * 32 + row_l;

  float creg[2] = {0.f, 0.f};          /* c state lives in registers */

  for (int t = 0; t < T_; ++t) {
    const int cur = t & 1, prv = cur ^ 1;
    const unsigned short* xr0 = xe + ((size_t)t * B_ + mA0) * NE_;
    const unsigned short* xr1 = xe + ((size_t)t * B_ + mA1) * NE_;
    const unsigned short* hr0 = states + ((size_t)mA0 * TS + t) * N_; /* h(t-1) */
    const unsigned short* hr1 = states + ((size_t)mA1 * TS + t) * N_;
    const unsigned short* cr0 = cbf + (size_t)prv * BN + (size_t)mA0 * N_;
    const unsigned short* cr1 = cbf + (size_t)prv * BN + (size_t)mA1 * N_;

    /* ---- wait: h(t-1) published by same-mi group ---- */
    if (wave == 0) {
      const unsigned tgt = (unsigned)t;
      while (__hip_atomic_load(gflagQ + lane, __ATOMIC_RELAXED, __HIP_MEMORY_SCOPE_AGENT) < tgt) { }
    }
    __syncthreads();
    __builtin_amdgcn_fence(__ATOMIC_ACQUIRE, "workgroup");

    /* ---------------- Phase P: fi_f, fi_i, cu -> c2 ---------------- */
    short8 axh0[10], axh1[10];   /* register-cached x+h fragments (reused 3x) */
    f32x4 f0 = {0.f,0.f,0.f,0.f}, f1 = {0.f,0.f,0.f,0.f};
    f32x4 i0 = {0.f,0.f,0.f,0.f}, i1 = {0.f,0.f,0.f,0.f};
    f32x4 u0 = {0.f,0.f,0.f,0.f}, u1 = {0.f,0.f,0.f,0.f};
#pragma unroll
    for (int c = 0; c < 10; ++c) {
      const int k = (wave + 4 * c) * 32;
      short8 a0, a1;
      if (c < 2) {               /* x part (k < 256), L2-cached normal loads */
        a0 = *(const short8*)(xr0 + k + qo);
        a1 = *(const short8*)(xr1 + k + qo);
      } else {                   /* h part: t-indexed, fresh-by-construction */
        a0 = __builtin_nontemporal_load((const short8*)(hr0 + (k - NE_) + qo));
        a1 = __builtin_nontemporal_load((const short8*)(hr1 + (k - NE_) + qo));
      }
      axh0[c] = a0; axh1[c] = a1;
      short8 bf = *(const short8*)(bfp + k + qo);
      short8 bi = *(const short8*)(bip + k + qo);
      short8 bu = *(const short8*)(bup + k + qo);
      f0 = MFMA(a0, bf, f0);  f1 = MFMA(a1, bf, f1);
      i0 = MFMA(a0, bi, i0);  i1 = MFMA(a1, bi, i1);
      u0 = MFMA(a0, bu, u0);  u1 = MFMA(a1, bu, u1);
    }
#pragma unroll
    for (int c = 10; c < 18; ++c) {
      const int k = (wave + 4 * c) * 32;
      short8 a0 = ld8_agent(cr0 + (k - NE_ - N_) + qo);
      short8 a1 = ld8_agent(cr1 + (k - NE_ - N_) + qo);
      short8 bf = *(const short8*)(bfp + k + qo);
      short8 bi = *(const short8*)(bip + k + qo);
      f0 = MFMA(a0, bf, f0);  f1 = MFMA(a1, bf, f1);
      i0 = MFMA(a0, bi, i0);  i1 = MFMA(a1, bi, i1);
    }
#pragma unroll
    for (int r = 0; r < 4; ++r) {
      red[wave][0][r][lane] = f0[r];  red[wave][1][r][lane] = f1[r];
      red[wave][2][r][lane] = i0[r];  red[wave][3][r][lane] = i1[r];
      red[wave][4][r][lane] = u0[r];  red[wave][5][r][lane] = u1[r];
    }
    __syncthreads();
    /* elementwise: c2 = sig(f)*c + sig(i)*tanh(u); publish bf16 pair */
    {
      unsigned pack = 0;
#pragma unroll
      for (int j = 0; j < 2; ++j) {
        const int L = lbase + j;
        const float fv = red[0][gh][re][L] + red[1][gh][re][L] +
                         red[2][gh][re][L] + red[3][gh][re][L] + sb[0][colp * 2 + j];
        const float iv = red[0][2+gh][re][L] + red[1][2+gh][re][L] +
                         red[2][2+gh][re][L] + red[3][2+gh][re][L] + sb[1][colp * 2 + j];
        const float uv = red[0][4+gh][re][L] + red[1][4+gh][re][L] +
                         red[2][4+gh][re][L] + red[3][4+gh][re][L] + sb[2][colp * 2 + j];
        const float c2v = sigm(fv) * creg[j] + sigm(iv) * tanhfast(uv);
        creg[j] = c2v;
        pack |= (unsigned)f2bf(c2v) << (16 * j);
      }
      unsigned* p = cbf32 + (((size_t)cur * BN + (size_t)me * N_ + n0 + colp * 2) >> 1);
      __hip_atomic_store(p, pack, __ATOMIC_RELAXED, __HIP_MEMORY_SCOPE_AGENT);
    }
    /* ---- arrive P ---- */
    __builtin_amdgcn_fence(__ATOMIC_RELEASE, "workgroup");
    __builtin_amdgcn_s_waitcnt(0);
    __syncthreads();
    if (tid == 0)
      __hip_atomic_store(gflagP + ni, (unsigned)(t + 1), __ATOMIC_RELAXED, __HIP_MEMORY_SCOPE_AGENT);

    /* ---------------- Phase Q: hg -> h2 ---------------- */
    /* pre-pass: x+h chunks replayed from registers (no loads, no wait) */
    f32x4 h0 = {0.f,0.f,0.f,0.f}, h1 = {0.f,0.f,0.f,0.f};
#pragma unroll
    for (int c = 0; c < 10; ++c) {
      const int k = (wave + 4 * c) * 32;
      short8 bh = *(const short8*)(bhp + k + qo);
      h0 = MFMA(axh0[c], bh, h0);
      h1 = MFMA(axh1[c], bh, h1);
    }
    /* ---- wait: c2(t) published by same-mi group ---- */
    if (wave == 0) {
      const unsigned tgt = (unsigned)(t + 1);
      while (__hip_atomic_load(gflagP + lane, __ATOMIC_RELAXED, __HIP_MEMORY_SCOPE_AGENT) < tgt) { }
    }
    __syncthreads();
    __builtin_amdgcn_fence(__ATOMIC_ACQUIRE, "workgroup");
    const unsigned short* c2r0 = cbf + (size_t)cur * BN + (size_t)mA0 * N_;
    const unsigned short* c2r1 = cbf + (size_t)cur * BN + (size_t)mA1 * N_;
#pragma unroll
    for (int c = 10; c < 18; ++c) {
      const int k = (wave + 4 * c) * 32;
      short8 a0 = ld8_agent(c2r0 + (k - NE_ - N_) + qo);
      short8 a1 = ld8_agent(c2r1 + (k - NE_ - N_) + qo);
      short8 bh = *(const short8*)(bhp + k + qo);
      h0 = MFMA(a0, bh, h0);
      h1 = MFMA(a1, bh, h1);
    }
#pragma unroll
    for (int r = 0; r < 4; ++r) {
      red[wave][0][r][lane] = h0[r];
      red[wave][1][r][lane] = h1[r];
    }
    __syncthreads();
    /* elementwise: h2 = hg * tanh(c2); publish bf16 pair into states(t+1) */
    {
      unsigned pack = 0;
#pragma unroll
      for (int j = 0; j < 2; ++j) {
        const int L = lbase + j;
        const float hv = red[0][gh][re][L] + red[1][gh][re][L] +
                         red[2][gh][re][L] + red[3][gh][re][L] + sb[3][colp * 2 + j];
        const float h2 = hv * tanhfast(creg[j]);
        pack |= (unsigned)f2bf(h2) << (16 * j);
      }
      unsigned* p = states32 + (((size_t)me * TS + t + 1) * N_ + n0 + colp * 2 >> 1);
      __hip_atomic_store(p, pack, __ATOMIC_RELAXED, __HIP_MEMORY_SCOPE_AGENT);
    }
    /* ---- arrive Q ---- */
    __builtin_amdgcn_fence(__ATOMIC_RELEASE, "workgroup");
    __builtin_amdgcn_s_waitcnt(0);
    __syncthreads();
    if (tid == 0)
      __hip_atomic_store(gflagQ + ni, (unsigned)(t + 1), __ATOMIC_RELAXED, __HIP_MEMORY_SCOPE_AGENT);
  }
}

/* ---------------- epilogue: y = states @ W_out + b_out ---------------------- */
__global__ void __launch_bounds__(256) out_gemm(const char* __restrict__ ws,
                                                const float* __restrict__ b_out,
                                                float* __restrict__ y) {
  const unsigned short* states = (const unsigned short*)(ws + OFF_STATES);
  const unsigned short* Wt_out = (const unsigned short*)(ws + OFF_WTOUT);
  const int tid = threadIdx.x, wave = tid >> 6, lane = tid & 63;
  const int l15 = lane & 15, quad = lane >> 4, qo = quad * 8;
  const int msub = wave & 1, npair = wave >> 1;
  const size_t r0 = (size_t)blockIdx.x * 32;  /* 32 consecutive t, same m */
  const size_t mb = r0 >> 9;
  const unsigned short* arow =
      states + (mb * TS + (r0 & 511) + msub * 16 + l15 + 1) * N_;
  const unsigned short* b0p = Wt_out + (size_t)(npair * 64 + 0  + l15) * N_;
  const unsigned short* b1p = Wt_out + (size_t)(npair * 64 + 16 + l15) * N_;
  const unsigned short* b2p = Wt_out + (size_t)(npair * 64 + 32 + l15) * N_;
  const unsigned short* b3p = Wt_out + (size_t)(npair * 64 + 48 + l15) * N_;
  f32x4 a0 = {0.f,0.f,0.f,0.f}, a1 = {0.f,0.f,0.f,0.f};
  f32x4 a2 = {0.f,0.f,0.f,0.f}, a3 = {0.f,0.f,0.f,0.f};
#pragma unroll 8
  for (int c = 0; c < 32; ++c) {
    const int k = c * 32;
    short8 av = *(const short8*)(arow + k + qo);
    a0 = MFMA(av, *(const short8*)(b0p + k + qo), a0);
    a1 = MFMA(av, *(const short8*)(b1p + k + qo), a1);
    a2 = MFMA(av, *(const short8*)(b2p + k + qo), a2);
    a3 = MFMA(av, *(const short8*)(b3p + k + qo), a3);
  }
#pragma unroll
  for (int r = 0; r < 4; ++r) {
    const size_t m = r0 + msub * 16 + quad * 4 + r;
    y[m * NA_ + npair * 64 + 0  + l15] = a0[r] + b_out[npair * 64 + 0  + l15];
    y[m * NA_ + npair * 64 + 16 + l15] = a1[r] + b_out[npair * 64 + 16 + l15];
    y[m * NA_ + npair * 64 + 32 + l15] = a2[r] + b_out[npair * 64 + 32 + l15];
    y[m * NA_ + npair * 64 + 48 + l15] = a3[r] + b_out[npair * 64 + 48 + l15];
  }
}

/* ---------------- host ------------------------------------------------------ */
extern "C" void kernel_launch(void* const* d_in, const int* in_sizes, int n_in,
                              void* d_out, int out_size, void* d_ws, size_t ws_size,
                              hipStream_t stream) {
  const int*   x     = (const int*)d_in[0];
  const float* emb   = (const float*)d_in[1];
  const float* W_fi  = (const float*)d_in[2];
  const float* b_fi  = (const float*)d_in[3];
  const float* W_cu  = (const float*)d_in[4];
  const float* b_cu  = (const float*)d_in[5];
  const float* W_h   = (const float*)d_in[6];
  const float* b_h   = (const float*)d_in[7];
  const float* W_out = (const float*)d_in[8];
  const float* b_out = (const float*)d_in[9];
  char* ws = (char*)d_ws;
  float* y = (float*)d_out;
  (void)in_sizes; (void)n_in; (void)out_size; (void)ws_size; /* needs ~186 MB ws */

  transpose_to_bf16<<<dim3(2048 / 32, 2304 / 32), dim3(32, 8), 0, stream>>>(
      W_fi, (unsigned short*)(ws + OFF_WTFI), KFI, 2048);
  transpose_to_bf16<<<dim3(1024 / 32, 1280 / 32), dim3(32, 8), 0, stream>>>(
      W_cu, (unsigned short*)(ws + OFF_WTCU), KCU, 1024);
  transpose_to_bf16<<<dim3(1024 / 32, 2304 / 32), dim3(32, 8), 0, stream>>>(
      W_h, (unsigned short*)(ws + OFF_WTH), KFI, 1024);
  transpose_to_bf16<<<dim3(128 / 32, 1024 / 32), dim3(32, 8), 0, stream>>>(
      W_out, (unsigned short*)(ws + OFF_WTOUT), N_, 128);

  embed_kernel<<<T_ * B_, NE_, 0, stream>>>(x, emb, (unsigned short*)(ws + OFF_XE));

  zero_sync_region<<<514, 256, 0, stream>>>(ws);  /* flags + cbf, sc1 stores */
  zero_h0<<<128, 256, 0, stream>>>(ws);           /* h slot 0 per batch row  */

  char* wsp = ws;
  void* kargs[4] = { (void*)&wsp, (void*)&b_fi, (void*)&b_cu, (void*)&b_h };
  hipLaunchCooperativeKernel((void*)lstm_persistent, dim3(256), dim3(256),
                             kargs, 0, stream);

  out_gemm<<<(B_ * T_) / 32, 256, 0, stream>>>(ws, b_out, y);
}